// Round 1
// baseline (2421.889 us; speedup 1.0000x reference)
//
#include <hip/hip_runtime.h>
#include <hip/hip_bf16.h>
#include <cstdint>
#include <cstddef>

#define HIDDEN 1024
#define HEADS  16
#define HDIM   64
#define BATCH  2
#define SEQ    2048
#define MTOT   (BATCH*SEQ)   // 4096 rows
#define KSEL   1024          // k_keep = S * (1 - 0.5)
#define QT     8             // q rows per attention block

// ---------------------------------------------------------------------------
// GEMM: C = A(MxK) * W^T, W is (N x K) row-major.
// mode 0: plain store; mode 1: K-transposed store (KT[(b,h,d)][s]); mode 2: +bias
// ---------------------------------------------------------------------------
#define BM 128
#define BN 128
#define BKK 16

__global__ __launch_bounds__(256) void gemm_xwT(
    const float* __restrict__ A, const float* __restrict__ W,
    float* __restrict__ C, const float* __restrict__ bias, int mode)
{
    constexpr int K = HIDDEN, N = HIDDEN;
    __shared__ __align__(16) float As[BKK][BM];
    __shared__ __align__(16) float Ws[BKK][BN];
    const int t  = threadIdx.x;
    const int m0 = blockIdx.y * BM, n0 = blockIdx.x * BN;
    const int tm = t >> 4, tn = t & 15;
    const int lrow = t & 127;          // 0..127
    const int lk   = (t >> 7) * 8;     // 0 or 8

    float acc[8][8];
#pragma unroll
    for (int i = 0; i < 8; ++i)
#pragma unroll
        for (int j = 0; j < 8; ++j) acc[i][j] = 0.f;

    const float* aptr = A + (size_t)(m0 + lrow) * K + lk;
    const float* wptr = W + (size_t)(n0 + lrow) * K + lk;

    for (int k0 = 0; k0 < K; k0 += BKK) {
        float4 a0 = *(const float4*)(aptr + k0);
        float4 a1 = *(const float4*)(aptr + k0 + 4);
        float4 w0 = *(const float4*)(wptr + k0);
        float4 w1 = *(const float4*)(wptr + k0 + 4);
        __syncthreads();   // protect previous-iteration LDS reads
        As[lk+0][lrow]=a0.x; As[lk+1][lrow]=a0.y; As[lk+2][lrow]=a0.z; As[lk+3][lrow]=a0.w;
        As[lk+4][lrow]=a1.x; As[lk+5][lrow]=a1.y; As[lk+6][lrow]=a1.z; As[lk+7][lrow]=a1.w;
        Ws[lk+0][lrow]=w0.x; Ws[lk+1][lrow]=w0.y; Ws[lk+2][lrow]=w0.z; Ws[lk+3][lrow]=w0.w;
        Ws[lk+4][lrow]=w1.x; Ws[lk+5][lrow]=w1.y; Ws[lk+6][lrow]=w1.z; Ws[lk+7][lrow]=w1.w;
        __syncthreads();
#pragma unroll
        for (int kk = 0; kk < BKK; ++kk) {
            float a[8], b[8];
            *(float4*)&a[0] = *(const float4*)&As[kk][tm*8];
            *(float4*)&a[4] = *(const float4*)&As[kk][tm*8+4];
            *(float4*)&b[0] = *(const float4*)&Ws[kk][tn*8];
            *(float4*)&b[4] = *(const float4*)&Ws[kk][tn*8+4];
#pragma unroll
            for (int i = 0; i < 8; ++i)
#pragma unroll
                for (int j = 0; j < 8; ++j)
                    acc[i][j] += a[i] * b[j];
        }
    }

    if (mode == 1) {
        // scatter to KT[((b*16+h)*64+d)*2048 + s]
#pragma unroll
        for (int i = 0; i < 8; ++i) {
            int m = m0 + tm*8 + i; int bb = m >> 11; int ss = m & (SEQ-1);
#pragma unroll
            for (int j = 0; j < 8; ++j) {
                int n = n0 + tn*8 + j; int hh = n >> 6; int dd = n & 63;
                C[((size_t)((bb*HEADS + hh)*HDIM + dd))*SEQ + ss] = acc[i][j];
            }
        }
    } else {
#pragma unroll
        for (int i = 0; i < 8; ++i) {
            int m = m0 + tm*8 + i;
#pragma unroll
            for (int j4 = 0; j4 < 2; ++j4) {
                int n = n0 + tn*8 + j4*4;
                float4 v;
                v.x = acc[i][j4*4+0]; v.y = acc[i][j4*4+1];
                v.z = acc[i][j4*4+2]; v.w = acc[i][j4*4+3];
                if (mode == 2) {
                    v.x += bias[n+0]; v.y += bias[n+1];
                    v.z += bias[n+2]; v.w += bias[n+3];
                }
                *(float4*)&C[(size_t)m*N + n] = v;
            }
        }
    }
}

// ---------------------------------------------------------------------------
// Fused adaptive sparse attention.
// One block (256 thr) = 8 q-rows of one (b,h). Scores live in registers
// (8 rows x 8 cols/thread). Exact kth-largest via 4-pass radix select.
// ---------------------------------------------------------------------------
__device__ __forceinline__ unsigned f2ord(float f) {
    unsigned b = __float_as_uint(f);
    return (b & 0x80000000u) ? ~b : (b | 0x80000000u);  // monotonic float->uint
}

__global__ __launch_bounds__(256) void attn_sparse(
    const float* __restrict__ Q, const float* __restrict__ KT,
    const float* __restrict__ V, const float* __restrict__ thrp,
    float* __restrict__ O)
{
    __shared__ __align__(16) float qs[QT][HDIM];            // 2 KB
    __shared__ __align__(16) unsigned short p16[QT][SEQ];   // 32 KB (bf16 softmax weights)
    __shared__ __align__(16) unsigned scratch[4*QT*HDIM];   // 8 KB: hist (QT*256) / final reduce
    __shared__ __align__(16) float Vs[32][68];              // 8.5 KB, padded
    __shared__ float rowmax[QT], rowsum[QT], cthr[QT];
    __shared__ unsigned prefix[QT];
    __shared__ int krem[QT];
    __shared__ float wred[QT][4];

    const int t = threadIdx.x;
    const int lane = t & 63, wid = t >> 6;
    const int bh = blockIdx.x >> 8;        // SEQ/QT = 256 q-blocks per (b,h)
    const int qblk = blockIdx.x & 255;
    const int b = bh >> 4, h = bh & 15;
    const int q0 = qblk * QT;

    for (int j = t; j < QT*HDIM; j += 256)
        qs[j>>6][j&63] = Q[(size_t)(b*SEQ + q0 + (j>>6))*HIDDEN + h*HDIM + (j&63)];
    __syncthreads();

    // ---- phase A: scores. thread t owns columns {t*4..t*4+3} and {1024+t*4..+3}
    float sreg[QT][8];
#pragma unroll
    for (int r = 0; r < QT; ++r)
#pragma unroll
        for (int i = 0; i < 8; ++i) sreg[r][i] = 0.f;

    const float* ktb = KT + (size_t)bh * HDIM * SEQ;
#pragma unroll
    for (int half = 0; half < 2; ++half) {
        const float* kp = ktb + half*1024 + t*4;
#pragma unroll 2
        for (int d4 = 0; d4 < HDIM; d4 += 4) {
            float4 kv0 = *(const float4*)&kp[(size_t)(d4+0)*SEQ];
            float4 kv1 = *(const float4*)&kp[(size_t)(d4+1)*SEQ];
            float4 kv2 = *(const float4*)&kp[(size_t)(d4+2)*SEQ];
            float4 kv3 = *(const float4*)&kp[(size_t)(d4+3)*SEQ];
#pragma unroll
            for (int r = 0; r < QT; ++r) {
                float4 q4 = *(const float4*)&qs[r][d4];
                sreg[r][half*4+0] += q4.x*kv0.x + q4.y*kv1.x + q4.z*kv2.x + q4.w*kv3.x;
                sreg[r][half*4+1] += q4.x*kv0.y + q4.y*kv1.y + q4.z*kv2.y + q4.w*kv3.y;
                sreg[r][half*4+2] += q4.x*kv0.z + q4.y*kv1.z + q4.z*kv2.z + q4.w*kv3.z;
                sreg[r][half*4+3] += q4.x*kv0.w + q4.y*kv1.w + q4.z*kv2.w + q4.w*kv3.w;
            }
        }
    }
#pragma unroll
    for (int r = 0; r < QT; ++r)
#pragma unroll
        for (int i = 0; i < 8; ++i) sreg[r][i] *= 0.125f;   // 1/sqrt(64)

    // ---- phase B1: row max (over all scores; equals max over kept when any kept)
#pragma unroll
    for (int r = 0; r < QT; ++r) {
        float v = sreg[r][0];
#pragma unroll
        for (int i = 1; i < 8; ++i) v = fmaxf(v, sreg[r][i]);
        for (int off = 32; off > 0; off >>= 1) v = fmaxf(v, __shfl_down(v, off));
        if (lane == 0) wred[r][wid] = v;
    }
    __syncthreads();
    if (t < QT) rowmax[t] = fmaxf(fmaxf(wred[t][0], wred[t][1]),
                                  fmaxf(wred[t][2], wred[t][3]));

    // ---- phase B2: exact kth-largest (k=1024) via 4-pass radix select
    if (t < QT) { prefix[t] = 0u; krem[t] = KSEL; }
    unsigned* hist = scratch;
    for (int pass = 0; pass < 4; ++pass) {
        const int shift = 24 - pass*8;
        __syncthreads();                       // prefix/krem visible
        for (int j = t; j < QT*256; j += 256) hist[j] = 0u;
        __syncthreads();
#pragma unroll
        for (int r = 0; r < QT; ++r) {
            unsigned pfx = prefix[r];
#pragma unroll
            for (int i = 0; i < 8; ++i) {
                unsigned u = f2ord(sreg[r][i]);
                bool act = (pass == 0) || (((u ^ pfx) >> (shift + 8)) == 0u);
                if (act) atomicAdd(&hist[r*256 + ((u >> shift) & 255u)], 1u);
            }
        }
        __syncthreads();
        if (t < QT) {
            int r = t; unsigned cum = 0; int kr = krem[r]; unsigned bsel = 0;
            for (int bb = 255; bb >= 0; --bb) {
                unsigned c = hist[r*256 + (unsigned)bb];
                if (cum + c >= (unsigned)kr) { bsel = (unsigned)bb; break; }
                cum += c;
            }
            prefix[r] |= bsel << shift;
            krem[r] = kr - (int)cum;
        }
    }
    __syncthreads();
    if (t < QT) {
        unsigned u = prefix[t];
        unsigned bits = (u & 0x80000000u) ? (u ^ 0x80000000u) : ~u;
        float kf = __uint_as_float(bits);
        float th = fminf(fmaxf(thrp[0], 0.f), 1.f);
        cthr[t] = fmaxf(kf, th);               // keep <=> s >= max(kth, thr)
    }
    __syncthreads();

    // ---- phase B3: masked softmax weights -> bf16 into LDS (transpose for PV)
    float lsum[QT];
#pragma unroll
    for (int r = 0; r < QT; ++r) {
        const float m = rowmax[r], c = cthr[r];
        float s = 0.f;
#pragma unroll
        for (int half = 0; half < 2; ++half) {
            unsigned pk[2];
            unsigned short* pp = (unsigned short*)pk;
#pragma unroll
            for (int jj = 0; jj < 4; ++jj) {
                float sc = sreg[r][half*4+jj];
                float p = (sc >= c) ? expf(sc - m) : 0.f;
                s += p;
                unsigned u = __float_as_uint(p);
                u += 0x7fffu + ((u >> 16) & 1u);          // RNE to bf16
                pp[jj] = (unsigned short)(u >> 16);
            }
            *(uint2*)&p16[r][half*1024 + t*4] = *(uint2*)pk;
        }
        lsum[r] = s;
    }
#pragma unroll
    for (int r = 0; r < QT; ++r) {
        float v = lsum[r];
        for (int off = 32; off > 0; off >>= 1) v += __shfl_down(v, off);
        if (lane == 0) wred[r][wid] = v;
    }
    __syncthreads();
    if (t < QT) rowsum[t] = wred[t][0] + wred[t][1] + wred[t][2] + wred[t][3];
    __syncthreads();

    // ---- phase C: PV. thread = (d = lane, k-offset-group g = wave id)
    float acc[QT];
#pragma unroll
    for (int r = 0; r < QT; ++r) acc[r] = 0.f;
    const int d = lane;
    const int g = wid;
    const int vrow = t >> 3, vcol = (t & 7) * 8;

    for (int kt = 0; kt < SEQ/32; ++kt) {
        __syncthreads();                       // protect previous Vs reads
        const float* vsrc = &V[(size_t)(b*SEQ + kt*32 + vrow)*HIDDEN + h*HDIM + vcol];
        float4 x0 = *(const float4*)vsrc;
        float4 x1 = *(const float4*)(vsrc + 4);
        *(float4*)&Vs[vrow][vcol]   = x0;
        *(float4*)&Vs[vrow][vcol+4] = x1;
        __syncthreads();
        float vr[8];
#pragma unroll
        for (int jj = 0; jj < 8; ++jj) vr[jj] = Vs[g*8+jj][d];
        const int kb = kt*32 + g*8;
#pragma unroll
        for (int r = 0; r < QT; ++r) {
            uint4 pv = *(const uint4*)&p16[r][kb];   // 8 bf16, broadcast
            acc[r] += __uint_as_float(pv.x << 16)         * vr[0];
            acc[r] += __uint_as_float(pv.x & 0xffff0000u) * vr[1];
            acc[r] += __uint_as_float(pv.y << 16)         * vr[2];
            acc[r] += __uint_as_float(pv.y & 0xffff0000u) * vr[3];
            acc[r] += __uint_as_float(pv.z << 16)         * vr[4];
            acc[r] += __uint_as_float(pv.z & 0xffff0000u) * vr[5];
            acc[r] += __uint_as_float(pv.w << 16)         * vr[6];
            acc[r] += __uint_as_float(pv.w & 0xffff0000u) * vr[7];
        }
    }

    // ---- reduce the 4 k-offset groups, normalize, store
    __syncthreads();
    float* red = (float*)scratch;
#pragma unroll
    for (int r = 0; r < QT; ++r) red[(g*QT + r)*HDIM + d] = acc[r];
    __syncthreads();
    for (int o = t; o < QT*HDIM; o += 256) {
        int r = o >> 6, dd = o & 63;
        float s = red[r*HDIM + dd] + red[(QT + r)*HDIM + dd]
                + red[(2*QT + r)*HDIM + dd] + red[(3*QT + r)*HDIM + dd];
        O[(size_t)(b*SEQ + q0 + r)*HIDDEN + h*HDIM + dd] = s / rowsum[r];
    }
}

// ---------------------------------------------------------------------------
extern "C" void kernel_launch(void* const* d_in, const int* in_sizes, int n_in,
                              void* d_out, int out_size, void* d_ws, size_t ws_size,
                              hipStream_t stream)
{
    (void)in_sizes; (void)n_in; (void)out_size; (void)ws_size;
    const float* x  = (const float*)d_in[0];
    const float* Wq = (const float*)d_in[1];
    const float* Wk = (const float*)d_in[2];
    const float* Wv = (const float*)d_in[3];
    const float* Wo = (const float*)d_in[4];
    const float* bo = (const float*)d_in[5];
    const float* at = (const float*)d_in[6];
    float* out = (float*)d_out;

    char* ws = (char*)d_ws;
    const size_t MB16 = (size_t)MTOT * HIDDEN * sizeof(float);  // 16 MB each
    float* Qb  = (float*)(ws);
    float* KTb = (float*)(ws + MB16);
    float* Vb  = (float*)(ws + 2*MB16);
    float* Ob  = (float*)(ws + 3*MB16);

    dim3 gg(HIDDEN/BN, MTOT/BM, 1);
    gemm_xwT<<<gg, 256, 0, stream>>>(x, Wq, Qb,  nullptr, 0);
    gemm_xwT<<<gg, 256, 0, stream>>>(x, Wk, KTb, nullptr, 1);
    gemm_xwT<<<gg, 256, 0, stream>>>(x, Wv, Vb,  nullptr, 0);
    attn_sparse<<<BATCH*HEADS*(SEQ/QT), 256, 0, stream>>>(Qb, KTb, Vb, at, Ob);
    gemm_xwT<<<gg, 256, 0, stream>>>(Ob, Wo, out, bo, 2);
}

// Round 2
// 1281.984 us; speedup vs baseline: 1.8892x; 1.8892x over previous
//
#include <hip/hip_runtime.h>
#include <hip/hip_bf16.h>
#include <cstdint>
#include <cstddef>

#define HIDDEN 1024
#define HEADS  16
#define HDIM   64
#define BATCH  2
#define SEQ    2048
#define MTOT   (BATCH*SEQ)   // 4096 rows
#define KSEL   1024          // k_keep = S * (1 - 0.5)
#define QT     16            // q rows per attention block

typedef __attribute__((ext_vector_type(8))) short bf16x8;
typedef __attribute__((ext_vector_type(4))) float f32x4;

__device__ __forceinline__ unsigned short f2bf_rne(float f) {
    unsigned u = __float_as_uint(f);
    u += 0x7fffu + ((u >> 16) & 1u);
    return (unsigned short)(u >> 16);
}
__device__ __forceinline__ float bf2f(unsigned short h) {
    return __uint_as_float(((unsigned)h) << 16);
}
__device__ __forceinline__ int score_bucket(float v) {
    // deterministic across call sites: explicit fma, floor, clamp
    int b = (int)floorf(__fmaf_rn(v, 32.0f, 256.0f));
    return min(511, max(0, b));
}

// ---------------------------------------------------------------------------
// GEMM: C = A(MxK) * W^T, W is (N x K) row-major. fp32 vector-ALU compute.
// mode 2: fp32 store + bias (final projection)
// mode 3: bf16 hi/lo split, scaled, to [bh][s][d] layout (Q with scale=1/8, K)
// mode 4: bf16 hi only, to [bh][s][d] layout (V)
// ---------------------------------------------------------------------------
#define BM 128
#define BN 128
#define BKK 16

__global__ __launch_bounds__(256) void gemm_xwT(
    const float* __restrict__ A, const float* __restrict__ W,
    float* __restrict__ Cf, const float* __restrict__ bias,
    unsigned short* __restrict__ outHi, unsigned short* __restrict__ outLo,
    int mode, float scale)
{
    constexpr int K = HIDDEN, N = HIDDEN;
    __shared__ __align__(16) float As[BKK][BM];
    __shared__ __align__(16) float Ws[BKK][BN];
    const int t  = threadIdx.x;
    const int m0 = blockIdx.y * BM, n0 = blockIdx.x * BN;
    const int tm = t >> 4, tn = t & 15;
    const int lrow = t & 127;          // 0..127
    const int lk   = (t >> 7) * 8;     // 0 or 8

    float acc[8][8];
#pragma unroll
    for (int i = 0; i < 8; ++i)
#pragma unroll
        for (int j = 0; j < 8; ++j) acc[i][j] = 0.f;

    const float* aptr = A + (size_t)(m0 + lrow) * K + lk;
    const float* wptr = W + (size_t)(n0 + lrow) * K + lk;

    for (int k0 = 0; k0 < K; k0 += BKK) {
        float4 a0 = *(const float4*)(aptr + k0);
        float4 a1 = *(const float4*)(aptr + k0 + 4);
        float4 w0 = *(const float4*)(wptr + k0);
        float4 w1 = *(const float4*)(wptr + k0 + 4);
        __syncthreads();   // protect previous-iteration LDS reads
        As[lk+0][lrow]=a0.x; As[lk+1][lrow]=a0.y; As[lk+2][lrow]=a0.z; As[lk+3][lrow]=a0.w;
        As[lk+4][lrow]=a1.x; As[lk+5][lrow]=a1.y; As[lk+6][lrow]=a1.z; As[lk+7][lrow]=a1.w;
        Ws[lk+0][lrow]=w0.x; Ws[lk+1][lrow]=w0.y; Ws[lk+2][lrow]=w0.z; Ws[lk+3][lrow]=w0.w;
        Ws[lk+4][lrow]=w1.x; Ws[lk+5][lrow]=w1.y; Ws[lk+6][lrow]=w1.z; Ws[lk+7][lrow]=w1.w;
        __syncthreads();
#pragma unroll
        for (int kk = 0; kk < BKK; ++kk) {
            float a[8], b[8];
            *(float4*)&a[0] = *(const float4*)&As[kk][tm*8];
            *(float4*)&a[4] = *(const float4*)&As[kk][tm*8+4];
            *(float4*)&b[0] = *(const float4*)&Ws[kk][tn*8];
            *(float4*)&b[4] = *(const float4*)&Ws[kk][tn*8+4];
#pragma unroll
            for (int i = 0; i < 8; ++i)
#pragma unroll
                for (int j = 0; j < 8; ++j)
                    acc[i][j] += a[i] * b[j];
        }
    }

    if (mode == 2) {
#pragma unroll
        for (int i = 0; i < 8; ++i) {
            int m = m0 + tm*8 + i;
#pragma unroll
            for (int j4 = 0; j4 < 2; ++j4) {
                int n = n0 + tn*8 + j4*4;
                float4 v;
                v.x = acc[i][j4*4+0] + bias[n+0];
                v.y = acc[i][j4*4+1] + bias[n+1];
                v.z = acc[i][j4*4+2] + bias[n+2];
                v.w = acc[i][j4*4+3] + bias[n+3];
                *(float4*)&Cf[(size_t)m*N + n] = v;
            }
        }
    } else {
        // bf16 output(s) at [((b*16+h)*2048+s)*64+d]
#pragma unroll
        for (int i = 0; i < 8; ++i) {
            int m = m0 + tm*8 + i; int bb = m >> 11; int ss = m & (SEQ-1);
            int n0j = n0 + tn*8; int hh = n0j >> 6; int dd = n0j & 63;
            size_t base = ((size_t)(bb*HEADS + hh)*SEQ + ss)*HDIM + dd;
            unsigned hu[4], lu[4];
#pragma unroll
            for (int p2 = 0; p2 < 4; ++p2) {
                float v0 = acc[i][p2*2+0] * scale;
                float v1 = acc[i][p2*2+1] * scale;
                unsigned short h0 = f2bf_rne(v0), h1 = f2bf_rne(v1);
                hu[p2] = (unsigned)h0 | ((unsigned)h1 << 16);
                if (mode == 3) {
                    float r0 = v0 - bf2f(h0), r1 = v1 - bf2f(h1);   // exact residual
                    lu[p2] = (unsigned)f2bf_rne(r0) | ((unsigned)f2bf_rne(r1) << 16);
                }
            }
            uint4 hv; hv.x = hu[0]; hv.y = hu[1]; hv.z = hu[2]; hv.w = hu[3];
            *(uint4*)(outHi + base) = hv;
            if (mode == 3) {
                uint4 lv; lv.x = lu[0]; lv.y = lu[1]; lv.z = lu[2]; lv.w = lu[3];
                *(uint4*)(outLo + base) = lv;
            }
        }
    }
}

// ---------------------------------------------------------------------------
// V transpose: [bh][s][d] bf16 -> [bh][d][s] bf16 (contiguous s for PV B-frags)
// ---------------------------------------------------------------------------
__global__ __launch_bounds__(256) void transpose_v(
    const unsigned short* __restrict__ Vb, unsigned short* __restrict__ Vt)
{
    __shared__ __align__(16) unsigned short tile[64][72];
    const int t = threadIdx.x;
    const int bh = blockIdx.y;
    const int s0 = blockIdx.x * 64;
#pragma unroll
    for (int pass = 0; pass < 2; ++pass) {
        int sr = (t >> 3) + pass*32;
        int d8 = (t & 7) * 8;
        uint4 v = *(const uint4*)&Vb[((size_t)bh*SEQ + s0 + sr)*HDIM + d8];
        *(uint4*)&tile[sr][d8] = v;
    }
    __syncthreads();
#pragma unroll
    for (int pass = 0; pass < 2; ++pass) {
        int d = (t >> 3) + pass*32;
        int s8 = (t & 7) * 8;
        unsigned short tmp[8];
#pragma unroll
        for (int k = 0; k < 8; ++k) tmp[k] = tile[s8 + k][d];
        *(uint4*)&Vt[((size_t)bh*HDIM + d)*SEQ + s0 + s8] = *(uint4*)tmp;
    }
}

// ---------------------------------------------------------------------------
// Fused adaptive sparse attention, MFMA edition.
// Block = 256 thr (4 waves) = 16 q-rows of one (b,h). Each wave owns 512 keys.
// Scores live in MFMA C-layout registers (f32x4 x 32 per lane).
// QK^T: split-bf16 (hi*hi + hi*lo + lo*hi) -> ~fp32-accurate selection.
// Top-k: 512-bucket linear histogram + exact rank in cutoff bucket.
// PV: P (bf16) through per-wave LDS transpose, V bf16 [d][s], MFMA.
// ---------------------------------------------------------------------------
__global__ __launch_bounds__(256, 2) void attn_mfma(
    const unsigned short* __restrict__ Qh, const unsigned short* __restrict__ Ql,
    const unsigned short* __restrict__ Kh, const unsigned short* __restrict__ Kl,
    const unsigned short* __restrict__ Vt, const float* __restrict__ thrp,
    float* __restrict__ O)
{
    // union region: histogram (16*513 u32 = 32832 B) THEN per-wave P (4*10240 B)
    __shared__ __align__(16) unsigned char U[40960];
    __shared__ __align__(16) float cand[16][64];
    __shared__ __align__(16) float Olds[16][64];
    __shared__ float smax[4][16], ssum[4][16];
    __shared__ unsigned csum[16][16];
    __shared__ float gmax[16], gsum[16], cutv[16], cthr[16];
    __shared__ int bcut[16], resid[16];
    __shared__ unsigned ccnt[16];

    const int t = threadIdx.x;
    const int lane = t & 63, wid = t >> 6;
    const int g = lane >> 4, n16 = lane & 15;
    const int bh = blockIdx.x & 31;               // same-bh blocks share XCD (idx%8)
    const int q0 = (blockIdx.x >> 5) * QT;
    const int row0 = g * 4;                       // C-layout rows owned by this lane

    unsigned* hist = (unsigned*)U;                // [16][513] padded (+1 breaks bank alias)
    unsigned short* Pw = (unsigned short*)(U + wid*10240);  // [256 cols][20] col-major

    // ---------------- QK^T (split-bf16 MFMA) ----------------
    const size_t qoff = ((size_t)bh*SEQ + q0 + n16)*HDIM + g*8;
    bf16x8 aqh0 = *(const bf16x8*)(Qh + qoff);
    bf16x8 aqh1 = *(const bf16x8*)(Qh + qoff + 32);
    bf16x8 aql0 = *(const bf16x8*)(Ql + qoff);
    bf16x8 aql1 = *(const bf16x8*)(Ql + qoff + 32);

    const unsigned short* khb = Kh + (size_t)bh*SEQ*HDIM;
    const unsigned short* klb = Kl + (size_t)bh*SEQ*HDIM;

    f32x4 sc[32];
#pragma unroll
    for (int tt = 0; tt < 32; ++tt) {
        const size_t kb = ((size_t)(wid*512 + tt*16 + n16))*HDIM + g*8;
        bf16x8 bh0 = *(const bf16x8*)(khb + kb);
        bf16x8 bh1 = *(const bf16x8*)(khb + kb + 32);
        bf16x8 bl0 = *(const bf16x8*)(klb + kb);
        bf16x8 bl1 = *(const bf16x8*)(klb + kb + 32);
        f32x4 a = {0.f, 0.f, 0.f, 0.f};
        a = __builtin_amdgcn_mfma_f32_16x16x32_bf16(aqh0, bh0, a, 0, 0, 0);
        a = __builtin_amdgcn_mfma_f32_16x16x32_bf16(aqh1, bh1, a, 0, 0, 0);
        a = __builtin_amdgcn_mfma_f32_16x16x32_bf16(aqh0, bl0, a, 0, 0, 0);
        a = __builtin_amdgcn_mfma_f32_16x16x32_bf16(aqh1, bl1, a, 0, 0, 0);
        a = __builtin_amdgcn_mfma_f32_16x16x32_bf16(aql0, bh0, a, 0, 0, 0);
        a = __builtin_amdgcn_mfma_f32_16x16x32_bf16(aql1, bh1, a, 0, 0, 0);
        sc[tt] = a;
    }

    // ---------------- zero LDS + row max ----------------
    for (int j = t; j < 16*513; j += 256) hist[j] = 0u;
    for (int j = t; j < 16*64; j += 256) ((float*)Olds)[j] = 0.f;
    if (t < 16) ccnt[t] = 0u;

    float rmax[4];
#pragma unroll
    for (int r = 0; r < 4; ++r) {
        float v = sc[0][r];
#pragma unroll
        for (int tt = 1; tt < 32; ++tt) v = fmaxf(v, sc[tt][r]);
#pragma unroll
        for (int m = 1; m < 16; m <<= 1) v = fmaxf(v, __shfl_xor(v, m));
        rmax[r] = v;
    }
    if (n16 == 0) {
#pragma unroll
        for (int r = 0; r < 4; ++r) smax[wid][row0 + r] = rmax[r];
    }
    __syncthreads();
    if (t < 16) gmax[t] = fmaxf(fmaxf(smax[0][t], smax[1][t]),
                                fmaxf(smax[2][t], smax[3][t]));

    // ---------------- histogram (exact counts) ----------------
#pragma unroll
    for (int tt = 0; tt < 32; ++tt)
#pragma unroll
        for (int r = 0; r < 4; ++r) {
            int b = score_bucket(sc[tt][r]);
            atomicAdd(&hist[(row0 + r)*513 + b], 1u);
        }
    __syncthreads();

    // ---------------- scan: cutoff bucket + residual rank ----------------
    {
        int row = t >> 4, slot = t & 15;
        int btop = 512 - slot*32;            // exclusive upper bucket of this chunk
        unsigned s = 0;
        for (int b = btop - 32; b < btop; ++b) s += hist[row*513 + b];
        csum[row][slot] = s;
    }
    __syncthreads();
    {
        int row = t >> 4, slot = t & 15;
        unsigned cum = 0;
        for (int j = 0; j < slot; ++j) cum += csum[row][j];
        unsigned cs = csum[row][slot];
        if (cum < (unsigned)KSEL && cum + cs >= (unsigned)KSEL) {
            unsigned c2 = cum;
            for (int b = 512 - slot*32 - 1; b >= 512 - (slot+1)*32; --b) {
                unsigned hb = hist[row*513 + b];
                if (c2 + hb >= (unsigned)KSEL) { bcut[row] = b; resid[row] = KSEL - (int)c2; break; }
                c2 += hb;
            }
        }
    }
    __syncthreads();
    if (t < 16) cutv[t] = ((float)bcut[t] - 256.0f) * 0.03125f;  // fallback (bucket lo edge)

    // ---------------- gather cutoff-bucket candidates ----------------
#pragma unroll
    for (int tt = 0; tt < 32; ++tt)
#pragma unroll
        for (int r = 0; r < 4; ++r) {
            float v = sc[tt][r];
            int row = row0 + r;
            if (score_bucket(v) == bcut[row]) {
                unsigned idx = atomicAdd(&ccnt[row], 1u);
                if (idx < 64u) cand[row][idx] = v;
            }
        }
    __syncthreads();

    // ---------------- exact rank within candidates -> kth value ----------------
    {
        int row = t >> 4, slot = t & 15;
        int n = min((int)ccnt[row], 64);
        int r = resid[row];
        for (int i = slot; i < n; i += 16) {
            float c = cand[row][i];
            int gt = 0, ge = 0;
            for (int j = 0; j < n; ++j) {
                float x = cand[row][j];
                gt += (x > c); ge += (x >= c);
            }
            if (gt < r && ge >= r) cutv[row] = c;   // unique value == kth largest
        }
    }
    __syncthreads();
    if (t < 16) {
        float th = fminf(fmaxf(thrp[0], 0.f), 1.f);
        cthr[t] = fmaxf(cutv[t], th);               // keep <=> s >= max(kth, thr)
    }
    __syncthreads();

    // ---------------- softmax weights (unnormalized) in registers ----------------
    float mrow[4], crow[4], lsum[4];
#pragma unroll
    for (int r = 0; r < 4; ++r) {
        mrow[r] = gmax[row0 + r]; crow[r] = cthr[row0 + r]; lsum[r] = 0.f;
    }
#pragma unroll
    for (int tt = 0; tt < 32; ++tt)
#pragma unroll
        for (int r = 0; r < 4; ++r) {
            float v = sc[tt][r];
            float p = (v >= crow[r]) ? __expf(v - mrow[r]) : 0.f;
            sc[tt][r] = p;
            lsum[r] += p;
        }
#pragma unroll
    for (int r = 0; r < 4; ++r) {
#pragma unroll
        for (int m = 1; m < 16; m <<= 1) lsum[r] += __shfl_xor(lsum[r], m);
    }
    if (n16 == 0) {
#pragma unroll
        for (int r = 0; r < 4; ++r) ssum[wid][row0 + r] = lsum[r];
    }
    __syncthreads();
    if (t < 16) gsum[t] = ssum[0][t] + ssum[1][t] + ssum[2][t] + ssum[3][t];

    // ---------------- PV (bf16 MFMA), two 256-col halves through LDS ----------------
    f32x4 oacc[4];
#pragma unroll
    for (int dt = 0; dt < 4; ++dt) oacc[dt] = (f32x4){0.f, 0.f, 0.f, 0.f};
    const unsigned short* vtb = Vt + (size_t)bh*HDIM*SEQ;

#pragma unroll
    for (int half = 0; half < 2; ++half) {
        __syncthreads();   // previous half fully consumed (also orders hist->P reuse)
#pragma unroll
        for (int tt2 = 0; tt2 < 16; ++tt2) {
            int tt = half*16 + tt2;
            int c = tt2*16 + n16;                 // col within this wave's half
            unsigned pk0 = (unsigned)f2bf_rne(sc[tt][0]) | ((unsigned)f2bf_rne(sc[tt][1]) << 16);
            unsigned pk1 = (unsigned)f2bf_rne(sc[tt][2]) | ((unsigned)f2bf_rne(sc[tt][3]) << 16);
            uint2 pk; pk.x = pk0; pk.y = pk1;
            *(uint2*)(Pw + (size_t)c*20 + row0) = pk;   // rows row0..row0+3 of col c
        }
        __syncthreads();
#pragma unroll
        for (int kc = 0; kc < 8; ++kc) {
            bf16x8 af;
#pragma unroll
            for (int j = 0; j < 8; ++j)
                af[j] = ((const short*)Pw)[(kc*32 + g*8 + j)*20 + n16];  // A[m=n16][k]
            const int sbase = wid*512 + half*256 + kc*32 + g*8;
#pragma unroll
            for (int dt = 0; dt < 4; ++dt) {
                const size_t vb = ((size_t)(dt*16 + n16))*SEQ + sbase;
                bf16x8 bf = *(const bf16x8*)(vtb + vb);
                oacc[dt] = __builtin_amdgcn_mfma_f32_16x16x32_bf16(af, bf, oacc[dt], 0, 0, 0);
            }
        }
    }

    // ---------------- cross-wave O reduce + normalized writeout ----------------
    __syncthreads();
#pragma unroll
    for (int dt = 0; dt < 4; ++dt)
#pragma unroll
        for (int r = 0; r < 4; ++r)
            atomicAdd(&Olds[row0 + r][dt*16 + n16], oacc[dt][r]);
    __syncthreads();
    {
        int row = t >> 4, d4 = (t & 15) * 4;
        float inv = 1.0f / gsum[row];
        float4 o;
        o.x = Olds[row][d4+0] * inv;
        o.y = Olds[row][d4+1] * inv;
        o.z = Olds[row][d4+2] * inv;
        o.w = Olds[row][d4+3] * inv;
        const int b = bh >> 4, h = bh & 15;
        *(float4*)&O[((size_t)(b*SEQ + q0 + row))*HIDDEN + h*HDIM + d4] = o;
    }
}

// ---------------------------------------------------------------------------
extern "C" void kernel_launch(void* const* d_in, const int* in_sizes, int n_in,
                              void* d_out, int out_size, void* d_ws, size_t ws_size,
                              hipStream_t stream)
{
    (void)in_sizes; (void)n_in; (void)out_size; (void)ws_size;
    const float* x  = (const float*)d_in[0];
    const float* Wq = (const float*)d_in[1];
    const float* Wk = (const float*)d_in[2];
    const float* Wv = (const float*)d_in[3];
    const float* Wo = (const float*)d_in[4];
    const float* bo = (const float*)d_in[5];
    const float* at = (const float*)d_in[6];
    float* out = (float*)d_out;

    char* ws = (char*)d_ws;
    const size_t NB16 = (size_t)MTOT * HIDDEN * sizeof(unsigned short);  // 8 MB
    unsigned short* Qhp = (unsigned short*)(ws);
    unsigned short* Qlp = (unsigned short*)(ws + 1*NB16);
    unsigned short* Khp = (unsigned short*)(ws + 2*NB16);
    unsigned short* Klp = (unsigned short*)(ws + 3*NB16);
    unsigned short* Vbp = (unsigned short*)(ws + 4*NB16);
    unsigned short* Vtp = (unsigned short*)(ws + 5*NB16);
    float*          Obp = (float*)         (ws + 6*NB16);                // 16 MB

    dim3 gg(HIDDEN/BN, MTOT/BM, 1);
    gemm_xwT<<<gg, 256, 0, stream>>>(x, Wq, nullptr, nullptr, Qhp, Qlp, 3, 0.125f);
    gemm_xwT<<<gg, 256, 0, stream>>>(x, Wk, nullptr, nullptr, Khp, Klp, 3, 1.0f);
    gemm_xwT<<<gg, 256, 0, stream>>>(x, Wv, nullptr, nullptr, Vbp, nullptr, 4, 1.0f);
    transpose_v<<<dim3(SEQ/64, BATCH*HEADS), 256, 0, stream>>>(Vbp, Vtp);
    attn_mfma<<<BATCH*HEADS*(SEQ/QT), 256, 0, stream>>>(Qhp, Qlp, Khp, Klp, Vtp, at, Obp);
    gemm_xwT<<<gg, 256, 0, stream>>>(Obp, Wo, out, bo, nullptr, nullptr, 2, 1.0f);
}

// Round 3
// 795.155 us; speedup vs baseline: 3.0458x; 1.6122x over previous
//
#include <hip/hip_runtime.h>
#include <hip/hip_bf16.h>
#include <cstdint>
#include <cstddef>

#define HIDDEN 1024
#define HEADS  16
#define HDIM   64
#define BATCH  2
#define SEQ    2048
#define MTOT   (BATCH*SEQ)   // 4096 rows
#define KSEL   1024          // k_keep = S * (1 - 0.5)
#define QT     16            // q rows per attention block

typedef __attribute__((ext_vector_type(8))) short bf16x8;
typedef __attribute__((ext_vector_type(4))) float f32x4;

__device__ __forceinline__ unsigned short f2bf_rne(float f) {
    unsigned u = __float_as_uint(f);
    u += 0x7fffu + ((u >> 16) & 1u);
    return (unsigned short)(u >> 16);
}
__device__ __forceinline__ float bf2f(unsigned short h) {
    return __uint_as_float(((unsigned)h) << 16);
}
__device__ __forceinline__ int score_bucket(float v) {
    int b = (int)floorf(__fmaf_rn(v, 32.0f, 256.0f));
    return min(511, max(0, b));
}
__device__ __forceinline__ void gl2lds16(const unsigned short* g, unsigned short* l) {
    __builtin_amdgcn_global_load_lds(
        (const __attribute__((address_space(1))) unsigned int*)g,
        (__attribute__((address_space(3))) unsigned int*)l, 16, 0, 0);
}

// ---------------------------------------------------------------------------
// fp32 -> bf16 hi/lo split (memory-bound prep)
// ---------------------------------------------------------------------------
__global__ __launch_bounds__(256) void split_bf(
    const float* __restrict__ src, unsigned short* __restrict__ hi,
    unsigned short* __restrict__ lo, int n4)
{
    int i = blockIdx.x * 256 + threadIdx.x;
    if (i >= n4) return;
    float4 v = ((const float4*)src)[i];
    unsigned short h0 = f2bf_rne(v.x), h1 = f2bf_rne(v.y);
    unsigned short h2 = f2bf_rne(v.z), h3 = f2bf_rne(v.w);
    uint2 hv, lv;
    hv.x = (unsigned)h0 | ((unsigned)h1 << 16);
    hv.y = (unsigned)h2 | ((unsigned)h3 << 16);
    lv.x = (unsigned)f2bf_rne(v.x - bf2f(h0)) | ((unsigned)f2bf_rne(v.y - bf2f(h1)) << 16);
    lv.y = (unsigned)f2bf_rne(v.z - bf2f(h2)) | ((unsigned)f2bf_rne(v.w - bf2f(h3)) << 16);
    *(uint2*)(hi + (size_t)i * 4) = hv;
    *(uint2*)(lo + (size_t)i * 4) = lv;
}

// ---------------------------------------------------------------------------
// Split-bf16 MFMA GEMM mainloop: D[n][m] = sum_k A[n][k]*B[m][k] (fp32 acc)
// A = weight (N x K) hi/lo, B = activation (M x K) hi/lo, 128x128 tile, BK=32.
// LDS chunks XOR-swizzled (c' = c ^ ((row>>1)&3)) -> 2-way-max bank aliasing.
// acc[i][j]: i = ntile (A rows), j = mtile (B rows);
// element (i,j,r): n = n0+wn*64+i*16+quad*4+r, m = m0+wm*64+j*16+n16.
// ---------------------------------------------------------------------------
__device__ __forceinline__ void gemm_mainloop(
    const unsigned short* __restrict__ Ah, const unsigned short* __restrict__ Al,
    const unsigned short* __restrict__ Bh, const unsigned short* __restrict__ Bl,
    int n0, int m0, unsigned short* lds, f32x4 acc[4][4])
{
    const int t = threadIdx.x;
    const int lane = t & 63;
    const int wid = t >> 6;
    const int wn = wid & 1, wm = wid >> 1;
    const int quad = lane >> 4, n16 = lane & 15;

    unsigned short* lAh = lds;
    unsigned short* lAl = lds + 4096;
    unsigned short* lBh = lds + 8192;
    unsigned short* lBl = lds + 12288;

    // staging assignment: chunk cidx = p*256 + t -> row = cidx>>2, lds chunk c'=cidx&3,
    // global chunk c = c' ^ ((row>>1)&3)
    int rowp[2], cp[2];
#pragma unroll
    for (int p = 0; p < 2; ++p) {
        int cidx = p * 256 + t;
        rowp[p] = cidx >> 2;
        cp[p]   = (cidx & 3) ^ ((rowp[p] >> 1) & 3);
    }
    const int wbase = (t >> 6) * 64;   // wave-uniform chunk base

    int offA[4], offB[4];
#pragma unroll
    for (int i = 0; i < 4; ++i) {
        int ra = wn * 64 + i * 16 + n16;
        offA[i] = ra * 32 + (quad ^ ((ra >> 1) & 3)) * 8;
        int rb = wm * 64 + i * 16 + n16;
        offB[i] = rb * 32 + (quad ^ ((rb >> 1) & 3)) * 8;
    }

    for (int k0 = 0; k0 < HIDDEN; k0 += 32) {
        __syncthreads();   // previous iteration's LDS fully consumed
#pragma unroll
        for (int p = 0; p < 2; ++p) {
            const size_t aoff = (size_t)(n0 + rowp[p]) * HIDDEN + k0 + cp[p] * 8;
            const size_t boff = (size_t)(m0 + rowp[p]) * HIDDEN + k0 + cp[p] * 8;
            const int ldst = (p * 256 + wbase) * 8;
            gl2lds16(Ah + aoff, lAh + ldst);
            gl2lds16(Al + aoff, lAl + ldst);
            gl2lds16(Bh + boff, lBh + ldst);
            gl2lds16(Bl + boff, lBl + ldst);
        }
        __syncthreads();   // implies vmcnt(0): staged data visible

        bf16x8 fah[4], fal[4], fbh[4], fbl[4];
#pragma unroll
        for (int i = 0; i < 4; ++i) {
            fah[i] = *(const bf16x8*)(lAh + offA[i]);
            fal[i] = *(const bf16x8*)(lAl + offA[i]);
            fbh[i] = *(const bf16x8*)(lBh + offB[i]);
            fbl[i] = *(const bf16x8*)(lBl + offB[i]);
        }
#pragma unroll
        for (int i = 0; i < 4; ++i)
#pragma unroll
            for (int j = 0; j < 4; ++j) {
                acc[i][j] = __builtin_amdgcn_mfma_f32_16x16x32_bf16(fah[i], fbh[j], acc[i][j], 0, 0, 0);
                acc[i][j] = __builtin_amdgcn_mfma_f32_16x16x32_bf16(fah[i], fbl[j], acc[i][j], 0, 0, 0);
                acc[i][j] = __builtin_amdgcn_mfma_f32_16x16x32_bf16(fal[i], fbh[j], acc[i][j], 0, 0, 0);
            }
    }
}

// ---------------------------------------------------------------------------
// Fused QKV projection. z=0: Q (scale 1/8, hi/lo out), z=1: K (hi/lo out),
// z=2: V (hi only, direct transposed [bh][d][s] store).
// ---------------------------------------------------------------------------
__global__ __launch_bounds__(256) void qkv_gemm(
    const unsigned short* __restrict__ xh, const unsigned short* __restrict__ xl,
    const unsigned short* __restrict__ Wsp,
    unsigned short* __restrict__ Qh, unsigned short* __restrict__ Ql,
    unsigned short* __restrict__ Kh, unsigned short* __restrict__ Kl,
    unsigned short* __restrict__ Vt)
{
    __shared__ __align__(16) unsigned short lds[16384];
    const int z = blockIdx.z;
    const unsigned short* Wh = Wsp + (size_t)z * 2097152;
    const unsigned short* Wl = Wh + 1048576;
    const int m0 = blockIdx.x * 128, n0 = blockIdx.y * 128;

    f32x4 acc[4][4];
#pragma unroll
    for (int i = 0; i < 4; ++i)
#pragma unroll
        for (int j = 0; j < 4; ++j) acc[i][j] = (f32x4){0.f, 0.f, 0.f, 0.f};

    gemm_mainloop(Wh, Wl, xh, xl, n0, m0, lds, acc);

    const int t = threadIdx.x;
    const int lane = t & 63, wid = t >> 6;
    const int wn = wid & 1, wm = wid >> 1;
    const int quad = lane >> 4, n16 = lane & 15;
    const float scale = (z == 0) ? 0.125f : 1.0f;

    if (z < 2) {
        unsigned short* oh = z ? Kh : Qh;
        unsigned short* ol = z ? Kl : Ql;
#pragma unroll
        for (int i = 0; i < 4; ++i)
#pragma unroll
            for (int j = 0; j < 4; ++j) {
                int m  = m0 + wm * 64 + j * 16 + n16;
                int nn = n0 + wn * 64 + i * 16 + quad * 4;
                int bb = m >> 11, ss = m & (SEQ - 1);
                int hh = nn >> 6, dd = nn & 63;
                size_t base = ((size_t)(bb * HEADS + hh) * SEQ + ss) * HDIM + dd;
                unsigned short h[4], l[4];
#pragma unroll
                for (int r = 0; r < 4; ++r) {
                    float v = acc[i][j][r] * scale;
                    h[r] = f2bf_rne(v);
                    l[r] = f2bf_rne(v - bf2f(h[r]));
                }
                uint2 hv, lv;
                hv.x = (unsigned)h[0] | ((unsigned)h[1] << 16);
                hv.y = (unsigned)h[2] | ((unsigned)h[3] << 16);
                lv.x = (unsigned)l[0] | ((unsigned)l[1] << 16);
                lv.y = (unsigned)l[2] | ((unsigned)l[3] << 16);
                *(uint2*)(oh + base) = hv;
                *(uint2*)(ol + base) = lv;
            }
    } else {
#pragma unroll
        for (int i = 0; i < 4; ++i)
#pragma unroll
            for (int j = 0; j < 4; ++j) {
                int m  = m0 + wm * 64 + j * 16 + n16;
                int bb = m >> 11, ss = m & (SEQ - 1);
#pragma unroll
                for (int r = 0; r < 4; ++r) {
                    int nn = n0 + wn * 64 + i * 16 + quad * 4 + r;
                    int hh = nn >> 6, dd = nn & 63;
                    Vt[((size_t)(bb * HEADS + hh) * HDIM + dd) * SEQ + ss] =
                        f2bf_rne(acc[i][j][r]);
                }
            }
    }
}

// ---------------------------------------------------------------------------
// Final projection: out = O @ Wo^T + bias (fp32 out)
// ---------------------------------------------------------------------------
__global__ __launch_bounds__(256) void out_gemm(
    const unsigned short* __restrict__ Oh, const unsigned short* __restrict__ Ol,
    const unsigned short* __restrict__ Woh, const unsigned short* __restrict__ Wol,
    const float* __restrict__ bias, float* __restrict__ out)
{
    __shared__ __align__(16) unsigned short lds[16384];
    const int m0 = blockIdx.x * 128, n0 = blockIdx.y * 128;

    f32x4 acc[4][4];
#pragma unroll
    for (int i = 0; i < 4; ++i)
#pragma unroll
        for (int j = 0; j < 4; ++j) acc[i][j] = (f32x4){0.f, 0.f, 0.f, 0.f};

    gemm_mainloop(Woh, Wol, Oh, Ol, n0, m0, lds, acc);

    const int t = threadIdx.x;
    const int lane = t & 63, wid = t >> 6;
    const int wn = wid & 1, wm = wid >> 1;
    const int quad = lane >> 4, n16 = lane & 15;
#pragma unroll
    for (int i = 0; i < 4; ++i)
#pragma unroll
        for (int j = 0; j < 4; ++j) {
            int m  = m0 + wm * 64 + j * 16 + n16;
            int nn = n0 + wn * 64 + i * 16 + quad * 4;
            float4 v;
            v.x = acc[i][j][0] + bias[nn + 0];
            v.y = acc[i][j][1] + bias[nn + 1];
            v.z = acc[i][j][2] + bias[nn + 2];
            v.w = acc[i][j][3] + bias[nn + 3];
            *(float4*)&out[(size_t)m * HIDDEN + nn] = v;
        }
}

// ---------------------------------------------------------------------------
// Fused adaptive sparse attention (unchanged core from round 2; epilogue now
// emits bf16 hi/lo O for the split-bf16 out_gemm).
// ---------------------------------------------------------------------------
__global__ __launch_bounds__(256, 2) void attn_mfma(
    const unsigned short* __restrict__ Qh, const unsigned short* __restrict__ Ql,
    const unsigned short* __restrict__ Kh, const unsigned short* __restrict__ Kl,
    const unsigned short* __restrict__ Vt, const float* __restrict__ thrp,
    unsigned short* __restrict__ Oh, unsigned short* __restrict__ Ol)
{
    __shared__ __align__(16) unsigned char U[40960];
    __shared__ __align__(16) float cand[16][64];
    __shared__ __align__(16) float Olds[16][64];
    __shared__ float smax[4][16], ssum[4][16];
    __shared__ unsigned csum[16][16];
    __shared__ float gmax[16], gsum[16], cutv[16], cthr[16];
    __shared__ int bcut[16], resid[16];
    __shared__ unsigned ccnt[16];

    const int t = threadIdx.x;
    const int lane = t & 63, wid = t >> 6;
    const int g = lane >> 4, n16 = lane & 15;
    const int bh = blockIdx.x & 31;
    const int q0 = (blockIdx.x >> 5) * QT;
    const int row0 = g * 4;

    unsigned* hist = (unsigned*)U;                          // [16][513]
    unsigned short* Pw = (unsigned short*)(U + wid*10240);  // [256 cols][20]

    // ---------------- QK^T (split-bf16 MFMA) ----------------
    const size_t qoff = ((size_t)bh*SEQ + q0 + n16)*HDIM + g*8;
    bf16x8 aqh0 = *(const bf16x8*)(Qh + qoff);
    bf16x8 aqh1 = *(const bf16x8*)(Qh + qoff + 32);
    bf16x8 aql0 = *(const bf16x8*)(Ql + qoff);
    bf16x8 aql1 = *(const bf16x8*)(Ql + qoff + 32);

    const unsigned short* khb = Kh + (size_t)bh*SEQ*HDIM;
    const unsigned short* klb = Kl + (size_t)bh*SEQ*HDIM;

    f32x4 sc[32];
#pragma unroll
    for (int tt = 0; tt < 32; ++tt) {
        const size_t kb = ((size_t)(wid*512 + tt*16 + n16))*HDIM + g*8;
        bf16x8 bh0 = *(const bf16x8*)(khb + kb);
        bf16x8 bh1 = *(const bf16x8*)(khb + kb + 32);
        bf16x8 bl0 = *(const bf16x8*)(klb + kb);
        bf16x8 bl1 = *(const bf16x8*)(klb + kb + 32);
        f32x4 a = {0.f, 0.f, 0.f, 0.f};
        a = __builtin_amdgcn_mfma_f32_16x16x32_bf16(aqh0, bh0, a, 0, 0, 0);
        a = __builtin_amdgcn_mfma_f32_16x16x32_bf16(aqh1, bh1, a, 0, 0, 0);
        a = __builtin_amdgcn_mfma_f32_16x16x32_bf16(aqh0, bl0, a, 0, 0, 0);
        a = __builtin_amdgcn_mfma_f32_16x16x32_bf16(aqh1, bl1, a, 0, 0, 0);
        a = __builtin_amdgcn_mfma_f32_16x16x32_bf16(aql0, bh0, a, 0, 0, 0);
        a = __builtin_amdgcn_mfma_f32_16x16x32_bf16(aql1, bh1, a, 0, 0, 0);
        sc[tt] = a;
    }

    for (int j = t; j < 16*513; j += 256) hist[j] = 0u;
    for (int j = t; j < 16*64; j += 256) ((float*)Olds)[j] = 0.f;
    if (t < 16) ccnt[t] = 0u;

    float rmax[4];
#pragma unroll
    for (int r = 0; r < 4; ++r) {
        float v = sc[0][r];
#pragma unroll
        for (int tt = 1; tt < 32; ++tt) v = fmaxf(v, sc[tt][r]);
#pragma unroll
        for (int m = 1; m < 16; m <<= 1) v = fmaxf(v, __shfl_xor(v, m));
        rmax[r] = v;
    }
    if (n16 == 0) {
#pragma unroll
        for (int r = 0; r < 4; ++r) smax[wid][row0 + r] = rmax[r];
    }
    __syncthreads();
    if (t < 16) gmax[t] = fmaxf(fmaxf(smax[0][t], smax[1][t]),
                                fmaxf(smax[2][t], smax[3][t]));

#pragma unroll
    for (int tt = 0; tt < 32; ++tt)
#pragma unroll
        for (int r = 0; r < 4; ++r) {
            int b = score_bucket(sc[tt][r]);
            atomicAdd(&hist[(row0 + r)*513 + b], 1u);
        }
    __syncthreads();

    {
        int row = t >> 4, slot = t & 15;
        int btop = 512 - slot*32;
        unsigned s = 0;
        for (int b = btop - 32; b < btop; ++b) s += hist[row*513 + b];
        csum[row][slot] = s;
    }
    __syncthreads();
    {
        int row = t >> 4, slot = t & 15;
        unsigned cum = 0;
        for (int j = 0; j < slot; ++j) cum += csum[row][j];
        unsigned cs = csum[row][slot];
        if (cum < (unsigned)KSEL && cum + cs >= (unsigned)KSEL) {
            unsigned c2 = cum;
            for (int b = 512 - slot*32 - 1; b >= 512 - (slot+1)*32; --b) {
                unsigned hb = hist[row*513 + b];
                if (c2 + hb >= (unsigned)KSEL) { bcut[row] = b; resid[row] = KSEL - (int)c2; break; }
                c2 += hb;
            }
        }
    }
    __syncthreads();
    if (t < 16) cutv[t] = ((float)bcut[t] - 256.0f) * 0.03125f;

#pragma unroll
    for (int tt = 0; tt < 32; ++tt)
#pragma unroll
        for (int r = 0; r < 4; ++r) {
            float v = sc[tt][r];
            int row = row0 + r;
            if (score_bucket(v) == bcut[row]) {
                unsigned idx = atomicAdd(&ccnt[row], 1u);
                if (idx < 64u) cand[row][idx] = v;
            }
        }
    __syncthreads();

    {
        int row = t >> 4, slot = t & 15;
        int n = min((int)ccnt[row], 64);
        int r = resid[row];
        for (int i = slot; i < n; i += 16) {
            float c = cand[row][i];
            int gt = 0, ge = 0;
            for (int j = 0; j < n; ++j) {
                float x = cand[row][j];
                gt += (x > c); ge += (x >= c);
            }
            if (gt < r && ge >= r) cutv[row] = c;
        }
    }
    __syncthreads();
    if (t < 16) {
        float th = fminf(fmaxf(thrp[0], 0.f), 1.f);
        cthr[t] = fmaxf(cutv[t], th);
    }
    __syncthreads();

    float mrow[4], crow[4], lsum[4];
#pragma unroll
    for (int r = 0; r < 4; ++r) {
        mrow[r] = gmax[row0 + r]; crow[r] = cthr[row0 + r]; lsum[r] = 0.f;
    }
#pragma unroll
    for (int tt = 0; tt < 32; ++tt)
#pragma unroll
        for (int r = 0; r < 4; ++r) {
            float v = sc[tt][r];
            float p = (v >= crow[r]) ? __expf(v - mrow[r]) : 0.f;
            sc[tt][r] = p;
            lsum[r] += p;
        }
#pragma unroll
    for (int r = 0; r < 4; ++r) {
#pragma unroll
        for (int m = 1; m < 16; m <<= 1) lsum[r] += __shfl_xor(lsum[r], m);
    }
    if (n16 == 0) {
#pragma unroll
        for (int r = 0; r < 4; ++r) ssum[wid][row0 + r] = lsum[r];
    }
    __syncthreads();
    if (t < 16) gsum[t] = ssum[0][t] + ssum[1][t] + ssum[2][t] + ssum[3][t];

    f32x4 oacc[4];
#pragma unroll
    for (int dt = 0; dt < 4; ++dt) oacc[dt] = (f32x4){0.f, 0.f, 0.f, 0.f};
    const unsigned short* vtb = Vt + (size_t)bh*HDIM*SEQ;

#pragma unroll
    for (int half = 0; half < 2; ++half) {
        __syncthreads();
#pragma unroll
        for (int tt2 = 0; tt2 < 16; ++tt2) {
            int tt = half*16 + tt2;
            int c = tt2*16 + n16;
            unsigned pk0 = (unsigned)f2bf_rne(sc[tt][0]) | ((unsigned)f2bf_rne(sc[tt][1]) << 16);
            unsigned pk1 = (unsigned)f2bf_rne(sc[tt][2]) | ((unsigned)f2bf_rne(sc[tt][3]) << 16);
            uint2 pk; pk.x = pk0; pk.y = pk1;
            *(uint2*)(Pw + (size_t)c*20 + row0) = pk;
        }
        __syncthreads();
#pragma unroll
        for (int kc = 0; kc < 8; ++kc) {
            bf16x8 af;
#pragma unroll
            for (int j = 0; j < 8; ++j)
                af[j] = ((const short*)Pw)[(kc*32 + g*8 + j)*20 + n16];
            const int sbase = wid*512 + half*256 + kc*32 + g*8;
#pragma unroll
            for (int dt = 0; dt < 4; ++dt) {
                const size_t vb = ((size_t)(dt*16 + n16))*SEQ + sbase;
                bf16x8 bf = *(const bf16x8*)(vtb + vb);
                oacc[dt] = __builtin_amdgcn_mfma_f32_16x16x32_bf16(af, bf, oacc[dt], 0, 0, 0);
            }
        }
    }

    __syncthreads();
#pragma unroll
    for (int dt = 0; dt < 4; ++dt)
#pragma unroll
        for (int r = 0; r < 4; ++r)
            atomicAdd(&Olds[row0 + r][dt*16 + n16], oacc[dt][r]);
    __syncthreads();
    {
        int row = t >> 4, d4 = (t & 15) * 4;
        float inv = 1.0f / gsum[row];
        float o0 = Olds[row][d4+0] * inv, o1 = Olds[row][d4+1] * inv;
        float o2 = Olds[row][d4+2] * inv, o3 = Olds[row][d4+3] * inv;
        unsigned short h0 = f2bf_rne(o0), h1 = f2bf_rne(o1);
        unsigned short h2 = f2bf_rne(o2), h3 = f2bf_rne(o3);
        uint2 hv, lv;
        hv.x = (unsigned)h0 | ((unsigned)h1 << 16);
        hv.y = (unsigned)h2 | ((unsigned)h3 << 16);
        lv.x = (unsigned)f2bf_rne(o0 - bf2f(h0)) | ((unsigned)f2bf_rne(o1 - bf2f(h1)) << 16);
        lv.y = (unsigned)f2bf_rne(o2 - bf2f(h2)) | ((unsigned)f2bf_rne(o3 - bf2f(h3)) << 16);
        const int bb = bh >> 4, hh = bh & 15;
        size_t base = ((size_t)(bb*SEQ + q0 + row))*HIDDEN + hh*HDIM + d4;
        *(uint2*)(Oh + base) = hv;
        *(uint2*)(Ol + base) = lv;
    }
}

// ---------------------------------------------------------------------------
extern "C" void kernel_launch(void* const* d_in, const int* in_sizes, int n_in,
                              void* d_out, int out_size, void* d_ws, size_t ws_size,
                              hipStream_t stream)
{
    (void)in_sizes; (void)n_in; (void)out_size; (void)ws_size;
    const float* x  = (const float*)d_in[0];
    const float* Wq = (const float*)d_in[1];
    const float* Wk = (const float*)d_in[2];
    const float* Wv = (const float*)d_in[3];
    const float* Wo = (const float*)d_in[4];
    const float* bo = (const float*)d_in[5];
    const float* at = (const float*)d_in[6];
    float* out = (float*)d_out;

    char* ws = (char*)d_ws;
    const size_t MB = 1048576;
    unsigned short* xh  = (unsigned short*)(ws);            // 8 MB; later Oh
    unsigned short* xl  = (unsigned short*)(ws + 8*MB);     // 8 MB; later Ol
    unsigned short* Wsp = (unsigned short*)(ws + 16*MB);    // 16 MB: 8 x 1M ushorts
    unsigned short* Qh  = (unsigned short*)(ws + 32*MB);
    unsigned short* Ql  = (unsigned short*)(ws + 40*MB);
    unsigned short* Kh  = (unsigned short*)(ws + 48*MB);
    unsigned short* Kl  = (unsigned short*)(ws + 56*MB);
    unsigned short* Vt  = (unsigned short*)d_out;           // front 8 MB of out (dead before out_gemm)

    split_bf<<<MTOT*HIDDEN/4/256, 256, 0, stream>>>(x,  xh, xl, MTOT*HIDDEN/4);
    split_bf<<<HIDDEN*HIDDEN/4/256, 256, 0, stream>>>(Wq, Wsp + 0u*1048576u, Wsp + 1u*1048576u, HIDDEN*HIDDEN/4);
    split_bf<<<HIDDEN*HIDDEN/4/256, 256, 0, stream>>>(Wk, Wsp + 2u*1048576u, Wsp + 3u*1048576u, HIDDEN*HIDDEN/4);
    split_bf<<<HIDDEN*HIDDEN/4/256, 256, 0, stream>>>(Wv, Wsp + 4u*1048576u, Wsp + 5u*1048576u, HIDDEN*HIDDEN/4);
    split_bf<<<HIDDEN*HIDDEN/4/256, 256, 0, stream>>>(Wo, Wsp + 6u*1048576u, Wsp + 7u*1048576u, HIDDEN*HIDDEN/4);

    qkv_gemm<<<dim3(MTOT/128, HIDDEN/128, 3), 256, 0, stream>>>(xh, xl, Wsp, Qh, Ql, Kh, Kl, Vt);
    attn_mfma<<<BATCH*HEADS*(SEQ/QT), 256, 0, stream>>>(Qh, Ql, Kh, Kl, Vt, at, xh, xl);
    out_gemm<<<dim3(MTOT/128, HIDDEN/128, 1), 256, 0, stream>>>(xh, xl, Wsp + 6u*1048576u, Wsp + 7u*1048576u, bo, out);
}